// Round 4
// baseline (292.493 us; speedup 1.0000x reference)
//
#include <hip/hip_runtime.h>

#define LEN 128
#define NB 32
#define NC 16
#define NU 16
#define NK 5
#define KQ 96
#define KQD 48
#define LUN 80

typedef unsigned int uint32;
typedef unsigned short u16;
typedef __attribute__((ext_vector_type(8))) short bf16x8;
typedef __attribute__((ext_vector_type(4))) float f32x4;

#define MFMA(a, b, c) __builtin_amdgcn_mfma_f32_16x16x32_bf16(a, b, c, 0, 0, 0)

static __device__ inline u16 f2bf(float f) {
    union { float f; uint32 u; } v; v.f = f;
    uint32 u = v.u;
    return (u16)((u + 0x7fffu + ((u >> 16) & 1u)) >> 16);
}
static __device__ inline uint32 pkbf(float a, float b) {
    return (uint32)f2bf(a) | ((uint32)f2bf(b) << 16);
}
static __device__ inline bf16x8 frag16(const void* p) { return *(const bf16x8*)p; }
static __device__ inline bf16x8 frag4(const uint32* p) {
    union { uint32 u[4]; bf16x8 v; } t;
    t.u[0] = p[0]; t.u[1] = p[1]; t.u[2] = p[2]; t.u[3] = p[3];
    return t.v;
}
static __device__ inline bf16x8 frag4s(const uint32* p, int stride) {
    union { uint32 u[4]; bf16x8 v; } t;
    t.u[0] = p[0]; t.u[1] = p[stride]; t.u[2] = p[2 * stride]; t.u[3] = p[3 * stride];
    return t.v;
}

__global__ __launch_bounds__(256) void k0_prep(const float* __restrict__ coefs,
                                               const float* __restrict__ cheb1,
                                               const float* __restrict__ cheb2,
                                               u16* __restrict__ cheb1T,
                                               u16* __restrict__ cheb2T,
                                               u16* __restrict__ coefTT) {
    int i = blockIdx.x * 256 + threadIdx.x;
    if (i < 81920) {
        int r = i >> 7, h = i & 127;
        int k = r >> 7, p = r & 127;
        cheb1T[i] = f2bf(cheb1[(k * LEN + h) * LEN + p]);
    } else if (i < 163840) {
        int j = i - 81920;
        int q = j / 640, t = j % 640;
        int l = t >> 7, w = t & 127;
        cheb2T[j] = f2bf(cheb2[(l * LEN + w) * LEN + q]);
    } else if (i < 171520) {
        int j = i - 163840;
        int lu = j / KQ, kap = j % KQ;
        int l = lu >> 4, u = lu & 15;
        int k2 = kap >> 5, rem = kap & 31, c = rem >> 1, tt = rem & 1;
        int k = 2 * k2 + tt;
        coefTT[j] = (k < NK) ? f2bf(coefs[((k * NK + l) * NC + c) * NU + u]) : (u16)0;
    }
}

__global__ __launch_bounds__(256, 3) void k1_mfma(const float* __restrict__ x,
                                                  const uint32* __restrict__ cheb1T,
                                                  uint32* __restrict__ t1d, int b0) {
    __shared__ uint32 Xs2[64 * 132];
    const int bl = blockIdx.x, c = blockIdx.y, b = b0 + bl;
    const int tid = threadIdx.x;
    const int lane = tid & 63;
    const int m16 = lane & 15, g = lane >> 4;
    const int wave = tid >> 6, wm = wave >> 1, wn = wave & 1;

    {
        const float* xp = x + (size_t)(b * NC + c) * (LEN * LEN);
        int w = tid & 127, hb = (tid >> 7) * 32;
        #pragma unroll 8
        for (int i = 0; i < 32; ++i) {
            int h2 = hb + i;
            Xs2[h2 * 132 + w] = pkbf(xp[(2 * h2) * LEN + w], xp[(2 * h2 + 1) * LEN + w]);
        }
    }
    __syncthreads();

    for (int pass = 0; pass < 4; ++pass) {
        const int P0 = pass * 32 + wm * 16;
        f32x4 acc[5][4];
        #pragma unroll
        for (int k = 0; k < 5; ++k)
            #pragma unroll
            for (int ni = 0; ni < 4; ++ni) acc[k][ni] = (f32x4)0.f;

        #pragma unroll
        for (int ks = 0; ks < 4; ++ks) {
            bf16x8 Af[5], Bf[4];
            #pragma unroll
            for (int k = 0; k < 5; ++k)
                Af[k] = frag16(cheb1T + (size_t)(k * 128 + P0 + m16) * 64 + ks * 16 + g * 4);
            #pragma unroll
            for (int ni = 0; ni < 4; ++ni)
                Bf[ni] = frag4s(Xs2 + (ks * 16 + g * 4) * 132 + wn * 64 + ni * 16 + m16, 132);
            #pragma unroll
            for (int k = 0; k < 5; ++k)
                #pragma unroll
                for (int ni = 0; ni < 4; ++ni)
                    acc[k][ni] = MFMA(Af[k], Bf[ni], acc[k][ni]);
        }

        #pragma unroll
        for (int ni = 0; ni < 4; ++ni) {
            int w = wn * 64 + ni * 16 + m16;
            #pragma unroll
            for (int r = 0; r < 4; ++r) {
                int p = P0 + g * 4 + r;
                uint32* dst = t1d + ((size_t)(bl * LEN + p) * LEN + w) * KQD + c;
                dst[0]  = pkbf(acc[0][ni][r], acc[1][ni][r]);
                dst[16] = pkbf(acc[2][ni][r], acc[3][ni][r]);
                dst[32] = pkbf(acc[4][ni][r], 0.f);
            }
        }
    }
}

__global__ __launch_bounds__(256, 3) void k2_mfma(const uint32* __restrict__ t1d,
                                                  const u16* __restrict__ coefTT,
                                                  const u16* __restrict__ cheb2T,
                                                  float* __restrict__ out, int b0) {
    __shared__ uint32 A3[32 * 326];
    const int bl = blockIdx.x, pg = blockIdx.y, b = b0 + bl;
    const int tid = threadIdx.x;
    const int lane = tid & 63, wave = tid >> 6;
    const int m16 = lane & 15, g = lane >> 4;
    const int wp = wave >> 1, ww = wave & 1;
    const int p = 2 * pg + wp;

    const uint32* arow = t1d + (size_t)(bl * LEN + p) * LEN * KQD;
    f32x4 acc[4][5];
    #pragma unroll
    for (int mi = 0; mi < 4; ++mi)
        #pragma unroll
        for (int n = 0; n < 5; ++n) acc[mi][n] = (f32x4)0.f;

    #pragma unroll
    for (int ks = 0; ks < 3; ++ks) {
        bf16x8 Af[4], Bf[5];
        #pragma unroll
        for (int mi = 0; mi < 4; ++mi) {
            int w = ww * 64 + mi * 16 + m16;
            Af[mi] = frag16(arow + (size_t)w * KQD + ks * 16 + g * 4);
        }
        #pragma unroll
        for (int n = 0; n < 5; ++n)
            Bf[n] = frag16(coefTT + (size_t)(n * 16 + m16) * KQ + ks * 32 + g * 8);
        #pragma unroll
        for (int mi = 0; mi < 4; ++mi)
            #pragma unroll
            for (int n = 0; n < 5; ++n)
                acc[mi][n] = MFMA(Af[mi], Bf[n], acc[mi][n]);
    }

    #pragma unroll
    for (int mi = 0; mi < 4; ++mi)
        #pragma unroll
        for (int n = 0; n < 5; ++n) {
            int lu = n * 16 + m16, l = lu >> 4, u = lu & 15;
            int w0 = ww * 64 + mi * 16 + g * 4;
            uint32* d = A3 + (wp * 16 + u) * 326 + l * 64 + (w0 >> 1);
            d[0] = pkbf(acc[mi][n][0], acc[mi][n][1]);
            d[1] = pkbf(acc[mi][n][2], acc[mi][n][3]);
        }
    __syncthreads();

    f32x4 c3[2][2];
    c3[0][0] = (f32x4)0.f; c3[0][1] = (f32x4)0.f;
    c3[1][0] = (f32x4)0.f; c3[1][1] = (f32x4)0.f;
    #pragma unroll 4
    for (int ks = 0; ks < 20; ++ks) {
        bf16x8 Af2[2], Bf2[2];
        #pragma unroll
        for (int mi = 0; mi < 2; ++mi)
            Af2[mi] = frag4(A3 + (mi * 16 + m16) * 326 + ks * 16 + g * 4);
        #pragma unroll
        for (int nt = 0; nt < 2; ++nt)
            Bf2[nt] = frag16(cheb2T + (size_t)(wave * 32 + nt * 16 + m16) * 640 + ks * 32 + g * 8);
        #pragma unroll
        for (int mi = 0; mi < 2; ++mi)
            #pragma unroll
            for (int nt = 0; nt < 2; ++nt)
                c3[mi][nt] = MFMA(Af2[mi], Bf2[nt], c3[mi][nt]);
    }

    #pragma unroll
    for (int mi = 0; mi < 2; ++mi)
        #pragma unroll
        for (int nt = 0; nt < 2; ++nt)
            #pragma unroll
            for (int r = 0; r < 4; ++r) {
                int u = g * 4 + r;
                int q = wave * 32 + nt * 16 + m16;
                out[(((size_t)(b * NU + u)) * LEN + (2 * pg + mi)) * LEN + q] = c3[mi][nt][r];
            }
}

extern "C" void kernel_launch(void* const* d_in, const int* in_sizes, int n_in,
                              void* d_out, int out_size, void* d_ws, size_t ws_size,
                              hipStream_t stream) {
    const float* x     = (const float*)d_in[0];
    const float* coefs = (const float*)d_in[1];
    const float* cheb1 = (const float*)d_in[2];
    const float* cheb2 = (const float*)d_in[3];
    float* out = (float*)d_out;

    const size_t aux_bytes = 163840 + 163840 + 15360;
    size_t aux_off = (ws_size - aux_bytes) & ~(size_t)255;
    u16* cheb1T = (u16*)((char*)d_ws + aux_off);
    u16* cheb2T = cheb1T + 81920;
    u16* coefTT = cheb2T + 81920;
    uint32* t1d = (uint32*)d_ws;

    const size_t per_b = (size_t)LEN * LEN * KQD * 4;
    int chunk = (int)(aux_off / per_b);
    if (chunk < 1) chunk = 1;
    if (chunk > NB) chunk = NB;

    hipLaunchKernelGGL(k0_prep, dim3((171520 + 255) / 256), dim3(256), 0, stream,
                       coefs, cheb1, cheb2, cheb1T, cheb2T, coefTT);
    for (int b0 = 0; b0 < NB; b0 += chunk) {
        int cb = (NB - b0 < chunk) ? (NB - b0) : chunk;
        hipLaunchKernelGGL(k1_mfma, dim3(cb, NC), dim3(256), 0, stream,
                           x, (const uint32*)cheb1T, t1d, b0);
        hipLaunchKernelGGL(k2_mfma, dim3(cb, 64), dim3(256), 0, stream,
                           t1d, coefTT, cheb2T, out, b0);
    }
}

// Round 5
// 204.908 us; speedup vs baseline: 1.4274x; 1.4274x over previous
//
#include <hip/hip_runtime.h>

#define LEN 128
#define NB 32
#define NC 16
#define NU 16
#define NK 5
#define KC 80          // (k,c) pairs, kc = k*16+c
#define KCP 96         // padded K for stage2
#define LUN 80

typedef unsigned int uint32;
typedef unsigned short u16;
typedef __attribute__((ext_vector_type(8))) short bf16x8;
typedef __attribute__((ext_vector_type(4))) float f32x4;

#define MFMA(a, b, c) __builtin_amdgcn_mfma_f32_16x16x32_bf16(a, b, c, 0, 0, 0)

static __device__ inline u16 f2bf(float f) {
    union { float f; uint32 u; } v; v.f = f;
    uint32 u = v.u;
    return (u16)((u + 0x7fffu + ((u >> 16) & 1u)) >> 16);   // RNE
}
static __device__ inline uint32 pkbf(float a, float b) {    // low=a, high=b
    return (uint32)f2bf(a) | ((uint32)f2bf(b) << 16);
}
static __device__ inline bf16x8 frag16(const void* p) { return *(const bf16x8*)p; }
static __device__ inline bf16x8 frag4(const uint32* p) {    // 4B-aligned, contiguous
    union { uint32 u[4]; bf16x8 v; } t;
    t.u[0] = p[0]; t.u[1] = p[1]; t.u[2] = p[2]; t.u[3] = p[3];
    return t.v;
}

// ---------------- k0_prep: bf16 operand layouts (as R3) ----------------
__global__ __launch_bounds__(256) void k0_prep(const float* __restrict__ coefs,
                                               const float* __restrict__ cheb1,
                                               const float* __restrict__ cheb2,
                                               u16* __restrict__ cheb1T,
                                               u16* __restrict__ cheb2T,
                                               u16* __restrict__ coefTT) {
    int i = blockIdx.x * 256 + threadIdx.x;
    if (i < 81920) {
        int r = i >> 7, h = i & 127;
        int k = r >> 7, p = r & 127;
        cheb1T[i] = f2bf(cheb1[(k * LEN + h) * LEN + p]);
    } else if (i < 163840) {
        int j = i - 81920;
        int q = j / 640, t = j % 640;
        int l = t >> 7, w = t & 127;
        cheb2T[j] = f2bf(cheb2[(l * LEN + w) * LEN + q]);
    } else if (i < 171520) {
        int j = i - 163840;
        int lu = j / KCP, kc = j % KCP;
        int l = lu >> 4, u = lu & 15, k = kc >> 4, c = kc & 15;
        coefTT[j] = (kc < KCP && kc < KC) ? f2bf(coefs[((k * NK + l) * NC + c) * NU + u]) : (u16)0;
    }
}

// ---------------- k0_xT: x[b][c][h][w] f32 -> xT[bc][w][h2] bf16-pair dwords
__global__ __launch_bounds__(256) void k0_xT(const float* __restrict__ x,
                                             uint32* __restrict__ xT) {
    __shared__ float Ls[32][131];
    const int bc = blockIdx.x;
    const float* xp = x + (size_t)bc * (LEN * LEN);
    uint32* op = xT + (size_t)bc * (LEN * 64);
    const int tid = threadIdx.x;

    for (int slab = 0; slab < 4; ++slab) {
        __syncthreads();   // prev-iter Ls readers done
        {   // stage 32 h-rows x 128 w, coalesced float4
            int h = tid >> 3, wq = tid & 7;
            const float* src = xp + (size_t)(slab * 32 + h) * LEN + wq * 16;
            #pragma unroll
            for (int j = 0; j < 4; ++j) {
                float4 v = *(const float4*)(src + 4 * j);
                Ls[h][wq * 16 + 4 * j + 0] = v.x;
                Ls[h][wq * 16 + 4 * j + 1] = v.y;
                Ls[h][wq * 16 + 4 * j + 2] = v.z;
                Ls[h][wq * 16 + 4 * j + 3] = v.w;
            }
        }
        __syncthreads();
        {   // write out transposed: lanes h2-contiguous -> 64B runs
            int h2 = tid & 15, wg = tid >> 4;
            #pragma unroll
            for (int ww = 0; ww < 8; ++ww) {
                int w = wg * 8 + ww;
                op[(size_t)w * 64 + slab * 16 + h2] = pkbf(Ls[2 * h2][w], Ls[2 * h2 + 1][w]);
            }
        }
    }
}

// ---------------- k1: t1[bl][p][k][c][w] = sum_h cheb1[k][h][p]*x[b][c][h][w]
// LDS-free: A = xT rows (M=w), B = cheb1T rows (N=kp window of 160), K=128 h.
// grid (8, 4, 2*cb): c = x + 8*(z&1), kpw = y, bl = z>>1  (same (c,bl) => ids = +8 => same XCD)
__global__ __launch_bounds__(256, 3) void k1_mfma(const uint32* __restrict__ xT,
                                                  const uint32* __restrict__ cheb1T,
                                                  u16* __restrict__ t1, int b0) {
    const int kpw = blockIdx.y, zz = blockIdx.z;
    const int c = blockIdx.x + 8 * (zz & 1);
    const int bl = zz >> 1;
    const int tid = threadIdx.x;
    const int lane = tid & 63, wave = tid >> 6;
    const int m16 = lane & 15, g = lane >> 4;
    const int wm = wave >> 1, wn = wave & 1;

    const uint32* xrow = xT + (size_t)((b0 + bl) * NC + c) * (LEN * 64);

    f32x4 acc[4][5];
    #pragma unroll
    for (int mi = 0; mi < 4; ++mi)
        #pragma unroll
        for (int ni = 0; ni < 5; ++ni) acc[mi][ni] = (f32x4)0.f;

    #pragma unroll
    for (int ks = 0; ks < 4; ++ks) {
        bf16x8 Af[4], Bf[5];
        #pragma unroll
        for (int mi = 0; mi < 4; ++mi)
            Af[mi] = frag16(xrow + (size_t)(wm * 64 + mi * 16 + m16) * 64 + ks * 16 + g * 4);
        #pragma unroll
        for (int ni = 0; ni < 5; ++ni)
            Bf[ni] = frag16(cheb1T + (size_t)(kpw * 160 + wn * 80 + ni * 16 + m16) * 64 + ks * 16 + g * 4);
        #pragma unroll
        for (int mi = 0; mi < 4; ++mi)
            #pragma unroll
            for (int ni = 0; ni < 5; ++ni)
                acc[mi][ni] = MFMA(Af[mi], Bf[ni], acc[mi][ni]);
    }

    // epilogue (R3-proven): lane holds 4 consecutive w at fixed kp -> uint2 stores
    #pragma unroll
    for (int ni = 0; ni < 5; ++ni) {
        int kp = kpw * 160 + wn * 80 + ni * 16 + m16;
        int k = kp >> 7, p = kp & 127;
        size_t base = (((size_t)(bl * LEN + p) * NK + k) * NC + c) * LEN;
        #pragma unroll
        for (int mi = 0; mi < 4; ++mi) {
            int w0 = wm * 64 + mi * 16 + g * 4;
            uint2 d;
            d.x = pkbf(acc[mi][ni][0], acc[mi][ni][1]);
            d.y = pkbf(acc[mi][ni][2], acc[mi][ni][3]);
            *(uint2*)(t1 + base + w0) = d;
        }
    }
}

// ---------------- k2: per (pg, bl) block, p = 2pg+{0,1} (R3 + stride-53 fix)
__global__ __launch_bounds__(256, 2) void k2_mfma(const u16* __restrict__ t1,
                                                  const u16* __restrict__ coefTT,
                                                  const u16* __restrict__ cheb2T,
                                                  float* __restrict__ out, int b0) {
    __shared__ uint32 sm[256 * 53];   // Ts [p][w][kc2] stride 53 dw; A3 aliases after barrier
    const int pg = blockIdx.x, bl = blockIdx.y, b = b0 + bl;
    const int tid = threadIdx.x;
    const int lane = tid & 63, wave = tid >> 6;
    const int n16 = lane & 15, g = lane >> 4;
    const int wp = wave >> 1, ww = wave & 1;

    // stage t1 (2 contiguous 20KB slices) -> Ts[w][kc-pairs]; stride 53 => writes 4-way max
    {
        const uint32* t1u = (const uint32*)(t1 + (size_t)(bl * LEN + 2 * pg) * (KC * LEN));
        #pragma unroll
        for (int i = 0; i < 5; ++i) {
            int it = tid + i * 256;          // 0..1279
            int p_i = (it >= 640) ? 1 : 0;
            int rem = it - 640 * p_i;
            int kc2 = rem >> 4, wq = rem & 15;
            const uint32* src = t1u + p_i * 5120 + kc2 * 128 + wq * 4;
            uint4 Av = *(const uint4*)(src);
            uint4 Bv = *(const uint4*)(src + 64);
            uint32* dst = sm + (p_i * 128 + wq * 8) * 53 + kc2;
            const uint32* av = (const uint32*)&Av;
            const uint32* bv = (const uint32*)&Bv;
            #pragma unroll
            for (int j = 0; j < 4; ++j) {
                dst[(2 * j) * 53]     = (av[j] & 0xffffu) | (bv[j] << 16);
                dst[(2 * j + 1) * 53] = (av[j] >> 16) | (bv[j] & 0xffff0000u);
            }
        }
        for (int j = tid; j < 2048; j += 256) {   // zero K-pad kc2 40..47
            int row = j >> 3, d = 40 + (j & 7);
            sm[row * 53 + d] = 0;
        }
    }
    __syncthreads();

    // stage2: s[w][lu], K=96
    f32x4 acc[4][5];
    #pragma unroll
    for (int mi = 0; mi < 4; ++mi)
        #pragma unroll
        for (int n = 0; n < 5; ++n) acc[mi][n] = (f32x4)0.f;

    #pragma unroll
    for (int ks = 0; ks < 3; ++ks) {
        bf16x8 Af[4], Bf[5];
        #pragma unroll
        for (int mi = 0; mi < 4; ++mi)
            Af[mi] = frag4(sm + (wp * 128 + ww * 64 + mi * 16 + n16) * 53 + ks * 16 + g * 4);
        #pragma unroll
        for (int n = 0; n < 5; ++n)
            Bf[n] = frag16(coefTT + (size_t)(n * 16 + n16) * KCP + ks * 32 + g * 8);
        #pragma unroll
        for (int mi = 0; mi < 4; ++mi)
            #pragma unroll
            for (int n = 0; n < 5; ++n)
                acc[mi][n] = MFMA(Af[mi], Bf[n], acc[mi][n]);
    }
    __syncthreads();   // all Ts reads done; A3 may overwrite

    // s -> A3 bf16 A-layout: row pu = wp*16+u (stride 326 dw), col (l*128+w)/2
    {
        uint32* A3 = sm;
        #pragma unroll
        for (int mi = 0; mi < 4; ++mi)
            #pragma unroll
            for (int n = 0; n < 5; ++n) {
                int lu = n * 16 + n16, l = lu >> 4, u = lu & 15;
                int w0 = ww * 64 + mi * 16 + g * 4;
                uint32* d = A3 + (wp * 16 + u) * 326 + l * 64 + (w0 >> 1);
                d[0] = pkbf(acc[mi][n][0], acc[mi][n][1]);
                d[1] = pkbf(acc[mi][n][2], acc[mi][n][3]);
            }
    }
    __syncthreads();

    // stage3: M=32 (pu), wave owns 32 q, K=640
    const uint32* A3 = sm;
    f32x4 c3[2][2];
    c3[0][0] = (f32x4)0.f; c3[0][1] = (f32x4)0.f;
    c3[1][0] = (f32x4)0.f; c3[1][1] = (f32x4)0.f;
    #pragma unroll 4
    for (int ks = 0; ks < 20; ++ks) {
        bf16x8 Af2[2], Bf2[2];
        #pragma unroll
        for (int mi = 0; mi < 2; ++mi)
            Af2[mi] = frag4(A3 + (mi * 16 + n16) * 326 + ks * 16 + g * 4);
        #pragma unroll
        for (int nt = 0; nt < 2; ++nt)
            Bf2[nt] = frag16(cheb2T + (size_t)(wave * 32 + nt * 16 + n16) * 640 + ks * 32 + g * 8);
        #pragma unroll
        for (int mi = 0; mi < 2; ++mi)
            #pragma unroll
            for (int nt = 0; nt < 2; ++nt)
                c3[mi][nt] = MFMA(Af2[mi], Bf2[nt], c3[mi][nt]);
    }

    #pragma unroll
    for (int mi = 0; mi < 2; ++mi)
        #pragma unroll
        for (int nt = 0; nt < 2; ++nt)
            #pragma unroll
            for (int r = 0; r < 4; ++r) {
                int u = g * 4 + r;
                int q = wave * 32 + nt * 16 + n16;
                out[(((size_t)(b * NU + u)) * LEN + (2 * pg + mi)) * LEN + q] = c3[mi][nt][r];
            }
}

extern "C" void kernel_launch(void* const* d_in, const int* in_sizes, int n_in,
                              void* d_out, int out_size, void* d_ws, size_t ws_size,
                              hipStream_t stream) {
    const float* x     = (const float*)d_in[0];
    const float* coefs = (const float*)d_in[1];
    const float* cheb1 = (const float*)d_in[2];
    const float* cheb2 = (const float*)d_in[3];
    float* out = (float*)d_out;

    const size_t xT_bytes = (size_t)NB * NC * LEN * 64 * 4;   // 16.78 MB
    const size_t aux_bytes = xT_bytes + 163840 + 163840 + 15360;
    size_t aux_off = (ws_size > aux_bytes + 256) ? ((ws_size - aux_bytes) & ~(size_t)255) : 0;

    uint32* xT  = (uint32*)((char*)d_ws + aux_off);
    u16* cheb1T = (u16*)((char*)xT + xT_bytes);
    u16* cheb2T = cheb1T + 81920;
    u16* coefTT = cheb2T + 81920;
    u16* t1 = (u16*)d_ws;

    const size_t per_b = (size_t)NK * NC * LEN * LEN * sizeof(u16);   // 2.62 MB
    int chunk = (int)(aux_off / per_b);
    if (chunk < 1) chunk = 1;
    if (chunk > NB) chunk = NB;

    hipLaunchKernelGGL(k0_prep, dim3((171520 + 255) / 256), dim3(256), 0, stream,
                       coefs, cheb1, cheb2, cheb1T, cheb2T, coefTT);
    hipLaunchKernelGGL(k0_xT, dim3(NB * NC), dim3(256), 0, stream, x, xT);

    for (int b0 = 0; b0 < NB; b0 += chunk) {
        int cb = (NB - b0 < chunk) ? (NB - b0) : chunk;
        hipLaunchKernelGGL(k1_mfma, dim3(8, 4, 2 * cb), dim3(256), 0, stream,
                           xT, (const uint32*)cheb1T, t1, b0);
        hipLaunchKernelGGL(k2_mfma, dim3(64, cb), dim3(256), 0, stream,
                           t1, coefTT, cheb2T, out, b0);
    }
}